// Round 9
// baseline (911.731 us; speedup 1.0000x reference)
//
#include <hip/hip_runtime.h>
#include <stdint.h>

#define Bsz   256
#define Tlen  1024
#define Vocab 128
#define Hdim  128
#define WTN   ((Vocab - 1) * Hdim)   // 127*128

typedef _Float16 half2_t __attribute__((ext_vector_type(2)));

// fast-path ws layout
#define PRE_BYTES ((size_t)Bsz * Tlen * Hdim * 2)        // 64 MiB f16
#define LEN_OFF   PRE_BYTES
#define WT_OFF    (PRE_BYTES + 1024)
#define WS_NEED   (WT_OFF + (size_t)WTN * 4 + 256)

__device__ __forceinline__ float tanh_fast(float x) {
    float e = __builtin_amdgcn_exp2f(x * 2.885390081777927f);
    return 1.0f - 2.0f * __builtin_amdgcn_rcpf(e + 1.0f);
}

// DPP quad helpers (proven R6): 0xB1=xor1, 0x4E=xor2, 0x141=row_half_mirror
#define DPPF(x, ctrl) __int_as_float(__builtin_amdgcn_mov_dpp(__float_as_int(x), ctrl, 0xF, 0xF, true))

// lgkm-only barrier: unlike __syncthreads, does NOT drain vmcnt, so global
// prefetch loads stay in flight across steps. Correct here: double-buffered
// h means no same-buffer WAR within a step; each wave drains its own LDS
// ops (write of DST, reads of SRC) before s_barrier.
#define BAR() asm volatile("s_waitcnt lgkmcnt(0)\n\ts_barrier" ::: "memory")

// h LDS layout (proven R6): 8 chunks of 16 f16 at 48-B stride, conflict-free b128.
#define HCHB  48
#define HBUFI (8 * HCHB / 4)   // 96 ints per buffer

// ---------- prep: transpose W_ih -> wt (V-1 x H), init lengths ----------
__global__ __launch_bounds__(256) void prep_kernel(
    const float* __restrict__ W_ih, float* __restrict__ wt, int* __restrict__ len_g)
{
    if (blockIdx.x == 0 && threadIdx.x < Bsz) len_g[threadIdx.x] = Tlen;
    int idx = blockIdx.x * 256 + threadIdx.x;
    if (idx < WTN) {
        int h = idx / (Vocab - 1);
        int f = idx - h * (Vocab - 1);
        wt[f * Hdim + h] = W_ih[idx];
    }
}

// ---------- decode: one-hot -> pre rows (f16 RTE) + lengths ----------
__global__ __launch_bounds__(256) void decode_kernel(
    const float* __restrict__ x, const float* __restrict__ wt,
    uint2* __restrict__ pre_all, int* __restrict__ len_g)
{
    const int l    = threadIdx.x & 63;
    const int half = l >> 5;
    const int li   = l & 31;
    const int row  = blockIdx.x * 8 + (threadIdx.x >> 6) * 2 + half;  // b*T + t

    const float4* xr = (const float4*)(x + (size_t)row * Vocab);
    float4 v = xr[li];
    int c = v.x > 0.5f ? 0 : v.y > 0.5f ? 1 : v.z > 0.5f ? 2 : v.w > 0.5f ? 3 : -1;
    unsigned long long m = __ballot(c >= 0);
    unsigned mh = half ? (unsigned)(m >> 32) : (unsigned)m;
    int fl  = __builtin_ctz(mh) + (half << 5);
    int sym = __shfl(li * 4 + c, fl, 64);

    if (sym == 0) {
        if (li == 0) atomicMin(&len_g[row >> 10], row & (Tlen - 1));
    } else {
        const float4* wr = (const float4*)(wt + (sym - 1) * Hdim);
        float4 wv = wr[li];    // pre elements 4li..4li+3
        unsigned e0 = __builtin_bit_cast(unsigned short, (_Float16)wv.x);
        unsigned e1 = __builtin_bit_cast(unsigned short, (_Float16)wv.y);
        unsigned e2 = __builtin_bit_cast(unsigned short, (_Float16)wv.z);
        unsigned e3 = __builtin_bit_cast(unsigned short, (_Float16)wv.w);
        uint2 o;
        o.x = e0 | (e1 << 16);
        o.y = e2 | (e3 << 16);
        pre_all[(size_t)row * 32 + li] = o;
    }
}

// ---------- RNN: PROVEN R6 loop, pre from global ring, lgkm-only barrier ----------
__global__ __launch_bounds__(512, 2) void rnn_kernel(
    const unsigned* __restrict__ pre_all, const int* __restrict__ len_g,
    const float* __restrict__ W_hh,
    const float* __restrict__ b_ih, const float* __restrict__ b_hh,
    const float* __restrict__ W_out, const float* __restrict__ b_out,
    float* __restrict__ out)
{
    __shared__ __align__(16) int hbuf[2][HBUFI];   // f16 h, double-buffered

    const int tid = threadIdx.x;
    const int b   = blockIdx.x;
    const int g   = tid >> 3;   // group 0..63, owns outputs 2g, 2g+1
    const int j   = tid & 7;    // K-chunk index (16 elements each)

    for (int k = tid; k < 2 * HBUFI; k += 512) ((int*)hbuf)[k] = 0;  // h0 = 0

    // W_hh rows 2g,2g+1, cols [16j,16j+16) -> 16 packed f16x2 (proven pack)
    int wp[16];
    #pragma unroll
    for (int r = 0; r < 2; r++) {
        const float4* wrow = (const float4*)(W_hh + (2 * g + r) * Hdim + 16 * j);
        #pragma unroll
        for (int q4 = 0; q4 < 4; q4++) {
            float4 t4 = wrow[q4];
            wp[r * 8 + q4 * 2 + 0] = __builtin_bit_cast(int, __builtin_amdgcn_cvt_pkrtz(t4.x, t4.y));
            wp[r * 8 + q4 * 2 + 1] = __builtin_bit_cast(int, __builtin_amdgcn_cvt_pkrtz(t4.z, t4.w));
        }
    }
    const float bias0 = b_ih[2 * g]     + b_hh[2 * g];
    const float bias1 = b_ih[2 * g + 1] + b_hh[2 * g + 1];

    const int len = len_g[b];
    // pre dword g of row t = f16 elements (2g, 2g+1) — same mapping as R6's wt2
    const unsigned* prow = pre_all + (size_t)b * Tlen * 64 + g;

    unsigned q0 = 0, q1 = 0, q2 = 0, q3 = 0;
    if (0 < len) q0 = prow[0];
    if (1 < len) q1 = prow[64];
    if (2 < len) q2 = prow[128];
    if (3 < len) q3 = prow[192];

    const char* hb0 = (const char*)hbuf[0];
    const char* hb1 = (const char*)hbuf[1];
    const int roff = j * HCHB;
    const int woff = (g >> 3) * HCHB + ((2 * g) & 15) * 2;

    __syncthreads();   // once: h0 + W visible

    for (int t = 0; t < len; t++) {
        #pragma unroll
        for (int k = 0; k < 16; k += 8)
            asm volatile("" : "+v"(wp[k]), "+v"(wp[k+1]), "+v"(wp[k+2]), "+v"(wp[k+3]),
                             "+v"(wp[k+4]), "+v"(wp[k+5]), "+v"(wp[k+6]), "+v"(wp[k+7]));

        unsigned qn = 0;
        if (t + 4 < len) qn = prow[(size_t)(t + 4) * 64];   // stays in flight 4 steps

        const char* hb = (t & 1) ? hb1 : hb0;
        uint4 r0 = *(const uint4*)(hb + roff);
        uint4 r1 = *(const uint4*)(hb + roff + 16);
        unsigned hr[8] = {r0.x, r0.y, r0.z, r0.w, r1.x, r1.y, r1.z, r1.w};
        float a0 = 0.0f, a1 = 0.0f;
        #pragma unroll
        for (int p = 0; p < 8; p++) {
            half2_t hh = __builtin_bit_cast(half2_t, hr[p]);
            a0 = __builtin_amdgcn_fdot2(hh, __builtin_bit_cast(half2_t, wp[p]),     a0, false);
            a1 = __builtin_amdgcn_fdot2(hh, __builtin_bit_cast(half2_t, wp[8 + p]), a1, false);
        }
        a0 += DPPF(a0, 0xB1);  a1 += DPPF(a1, 0xB1);
        a0 += DPPF(a0, 0x4E);  a1 += DPPF(a1, 0x4E);
        a0 += DPPF(a0, 0x141); a1 += DPPF(a1, 0x141);
        if (j == 0) {
            half2_t ph = __builtin_bit_cast(half2_t, q0);
            float h0 = tanh_fast(a0 + (float)ph.x + bias0);
            float h1 = tanh_fast(a1 + (float)ph.y + bias1);
            int pk = __builtin_bit_cast(int, __builtin_amdgcn_cvt_pkrtz(h0, h1));
            *(int*)(((char*)hbuf[(t + 1) & 1]) + woff) = pk;
        }
        q0 = q1; q1 = q2; q2 = q3; q3 = qn;
        BAR();
    }

    // epilogue (proven R6)
    const _Float16* hf = (const _Float16*)hbuf[len & 1];
    #define HGET(e) ((float)hf[((e) >> 4) * 24 + ((e) & 15)])
    if (tid < Hdim)
        out[2 * Bsz + b * Hdim + tid] = HGET(tid);
    if (tid < 64) {
        float h0 = HGET(tid);
        float h1 = HGET(tid + 64);
        float p0 = W_out[tid] * h0 + W_out[64 + tid] * h1;
        float p1 = W_out[128 + tid] * h0 + W_out[192 + tid] * h1;
        #pragma unroll
        for (int off = 32; off > 0; off >>= 1) {
            p0 += __shfl_down(p0, off, 64);
            p1 += __shfl_down(p1, off, 64);
        }
        if (tid == 0) {
            float l0 = p0 + b_out[0], l1 = p1 + b_out[1];
            float m  = fmaxf(l0, l1);
            float e0 = __expf(l0 - m), e1 = __expf(l1 - m);
            float d  = e0 + e1;
            out[b * 2 + 0] = e0 / d;
            out[b * 2 + 1] = e1 / d;
        }
    }
    #undef HGET
}

// ---------- fallback (R6 exact, proven) ----------
__global__ __launch_bounds__(512, 2) void rnn_fallback(
    const float* __restrict__ x, const float* __restrict__ wt,
    const float* __restrict__ W_hh,
    const float* __restrict__ b_ih, const float* __restrict__ b_hh,
    const float* __restrict__ W_out, const float* __restrict__ b_out,
    float* __restrict__ out)
{
    __shared__ float wt_s[WTN];
    __shared__ int   syms[Tlen];
    __shared__ __align__(16) int hbuf[2][HBUFI];
    __shared__ int   len_sh;

    const int tid = threadIdx.x;
    const int b   = blockIdx.x;
    const int g   = tid >> 3;
    const int j   = tid & 7;

    if (tid == 0) len_sh = Tlen;
    for (int k = tid; k < 2 * HBUFI; k += 512) ((int*)hbuf)[k] = 0;

    int wp[16];
    #pragma unroll
    for (int r = 0; r < 2; r++) {
        const float4* wrow = (const float4*)(W_hh + (2 * g + r) * Hdim + 16 * j);
        #pragma unroll
        for (int q4 = 0; q4 < 4; q4++) {
            float4 t4 = wrow[q4];
            wp[r * 8 + q4 * 2 + 0] = __builtin_bit_cast(int, __builtin_amdgcn_cvt_pkrtz(t4.x, t4.y));
            wp[r * 8 + q4 * 2 + 1] = __builtin_bit_cast(int, __builtin_amdgcn_cvt_pkrtz(t4.z, t4.w));
        }
    }
    const float bias0 = b_ih[2 * g]     + b_hh[2 * g];
    const float bias1 = b_ih[2 * g + 1] + b_hh[2 * g + 1];

    {
        const float4* src = (const float4*)wt;
        float4* dst = (float4*)wt_s;
        for (int k = tid; k < WTN / 4; k += 512) dst[k] = src[k];
    }
    const float4* xb = (const float4*)(x + (size_t)b * Tlen * Vocab);
    for (int k = tid; k < (Tlen * Vocab) / 4; k += 512) {
        float4 v = xb[k];
        int c = -1;
        if      (v.x > 0.5f) c = 0;
        else if (v.y > 0.5f) c = 1;
        else if (v.z > 0.5f) c = 2;
        else if (v.w > 0.5f) c = 3;
        if (c >= 0) syms[k >> 5] = ((k & 31) << 2) + c;
    }
    __syncthreads();
    {
        int lm = Tlen;
        for (int k = tid; k < Tlen; k += 512)
            if (syms[k] == 0 && k < lm) lm = k;
        if (lm < Tlen) atomicMin(&len_sh, lm);
    }
    __syncthreads();
    const int len = len_sh;

    const float2* wt2 = (const float2*)wt_s;
    float2 pre_v = {0.0f, 0.0f}, p_t1 = {0.0f, 0.0f};
    int s_t2 = 1;
    if (len > 0) pre_v = wt2[(syms[0] - 1) * 64 + g];
    if (len > 1) p_t1  = wt2[(syms[1] - 1) * 64 + g];
    if (len > 2) s_t2  = syms[2];

    const char* hb0 = (const char*)hbuf[0];
    const char* hb1 = (const char*)hbuf[1];
    const int roff = j * HCHB;
    const int woff = (g >> 3) * HCHB + ((2 * g) & 15) * 2;

    for (int t = 0; t < len; t++) {
        #pragma unroll
        for (int k = 0; k < 16; k += 8)
            asm volatile("" : "+v"(wp[k]), "+v"(wp[k+1]), "+v"(wp[k+2]), "+v"(wp[k+3]),
                             "+v"(wp[k+4]), "+v"(wp[k+5]), "+v"(wp[k+6]), "+v"(wp[k+7]));
        float2 p_t2 = wt2[(s_t2 - 1) * 64 + g];
        int   s_t3 = (t + 3 < len) ? syms[t + 3] : 1;

        const char* hb = (t & 1) ? hb1 : hb0;
        uint4 r0 = *(const uint4*)(hb + roff);
        uint4 r1 = *(const uint4*)(hb + roff + 16);
        unsigned hr[8] = {r0.x, r0.y, r0.z, r0.w, r1.x, r1.y, r1.z, r1.w};
        float a0 = 0.0f, a1 = 0.0f;
        #pragma unroll
        for (int p = 0; p < 8; p++) {
            half2_t hh = __builtin_bit_cast(half2_t, hr[p]);
            a0 = __builtin_amdgcn_fdot2(hh, __builtin_bit_cast(half2_t, wp[p]),     a0, false);
            a1 = __builtin_amdgcn_fdot2(hh, __builtin_bit_cast(half2_t, wp[8 + p]), a1, false);
        }
        a0 += DPPF(a0, 0xB1); a1 += DPPF(a1, 0xB1);
        a0 += DPPF(a0, 0x4E); a1 += DPPF(a1, 0x4E);
        a0 += DPPF(a0, 0x141); a1 += DPPF(a1, 0x141);
        if (j == 0) {
            float h0 = tanh_fast(a0 + pre_v.x + bias0);
            float h1 = tanh_fast(a1 + pre_v.y + bias1);
            int pk = __builtin_bit_cast(int, __builtin_amdgcn_cvt_pkrtz(h0, h1));
            *(int*)(((char*)hbuf[(t + 1) & 1]) + woff) = pk;
        }
        pre_v = p_t1; p_t1 = p_t2; s_t2 = s_t3;
        __syncthreads();
    }

    const _Float16* hf = (const _Float16*)hbuf[len & 1];
    #define HGET(e) ((float)hf[((e) >> 4) * 24 + ((e) & 15)])
    if (tid < Hdim)
        out[2 * Bsz + b * Hdim + tid] = HGET(tid);
    if (tid < 64) {
        float h0 = HGET(tid);
        float h1 = HGET(tid + 64);
        float p0 = W_out[tid] * h0 + W_out[64 + tid] * h1;
        float p1 = W_out[128 + tid] * h0 + W_out[192 + tid] * h1;
        #pragma unroll
        for (int off = 32; off > 0; off >>= 1) {
            p0 += __shfl_down(p0, off, 64);
            p1 += __shfl_down(p1, off, 64);
        }
        if (tid == 0) {
            float l0 = p0 + b_out[0], l1 = p1 + b_out[1];
            float m  = fmaxf(l0, l1);
            float e0 = __expf(l0 - m), e1 = __expf(l1 - m);
            float d  = e0 + e1;
            out[b * 2 + 0] = e0 / d;
            out[b * 2 + 1] = e1 / d;
        }
    }
    #undef HGET
}

extern "C" void kernel_launch(void* const* d_in, const int* in_sizes, int n_in,
                              void* d_out, int out_size, void* d_ws, size_t ws_size,
                              hipStream_t stream) {
    const float* x     = (const float*)d_in[0];
    const float* W_ih  = (const float*)d_in[1];
    const float* W_hh  = (const float*)d_in[2];
    const float* b_ih  = (const float*)d_in[3];
    const float* b_hh  = (const float*)d_in[4];
    const float* W_out = (const float*)d_in[5];
    const float* b_out = (const float*)d_in[6];
    float* out = (float*)d_out;

    const int NTRN = (WTN + 255) / 256;

    if (ws_size >= WS_NEED) {
        uint2* pre_all = (uint2*)d_ws;
        int*   len_g   = (int*)((char*)d_ws + LEN_OFF);
        float* wt      = (float*)((char*)d_ws + WT_OFF);
        prep_kernel<<<NTRN, 256, 0, stream>>>(W_ih, wt, len_g);
        decode_kernel<<<(Bsz * Tlen) / 8, 256, 0, stream>>>(x, wt, pre_all, len_g);
        rnn_kernel<<<Bsz, 512, 0, stream>>>((const unsigned*)pre_all, len_g,
                                            W_hh, b_ih, b_hh, W_out, b_out, out);
    } else {
        float* wt    = (float*)d_ws;
        int*   len_g = (int*)((char*)d_ws + (size_t)WTN * 4);
        prep_kernel<<<NTRN, 256, 0, stream>>>(W_ih, wt, len_g);
        rnn_fallback<<<Bsz, 512, 0, stream>>>(x, wt, W_hh, b_ih, b_hh,
                                              W_out, b_out, out);
    }
}

// Round 10
// 619.091 us; speedup vs baseline: 1.4727x; 1.4727x over previous
//
#include <hip/hip_runtime.h>
#include <stdint.h>

#define Bsz   256
#define Tlen  1024
#define Vocab 128
#define Hdim  128
#define WTN   ((Vocab - 1) * Hdim)   // 127*128

typedef _Float16 half2_t __attribute__((ext_vector_type(2)));

// fast-path ws layout: pre table (64 MiB f16) + syms (1 MiB) + wt (65 KiB)
#define PRE_BYTES ((size_t)Bsz * Tlen * Hdim * 2)
#define SYMS_OFF  PRE_BYTES
#define WT_OFF    (PRE_BYTES + (size_t)Bsz * Tlen * 4)
#define WS_NEED   (WT_OFF + (size_t)WTN * 4 + 256)

__device__ __forceinline__ float tanh_fast(float x) {
    float e = __builtin_amdgcn_exp2f(x * 2.885390081777927f);
    return 1.0f - 2.0f * __builtin_amdgcn_rcpf(e + 1.0f);
}

// DPP quad helpers (proven R6): 0xB1=xor1, 0x4E=xor2, 0x141=row_half_mirror
#define DPPF(x, ctrl) __int_as_float(__builtin_amdgcn_mov_dpp(__float_as_int(x), ctrl, 0xF, 0xF, true))

// lgkm-only barrier (proven R9): does NOT drain vmcnt, so the global pre
// prefetch ring stays in flight across steps.
#define BAR() asm volatile("s_waitcnt lgkmcnt(0)\n\ts_barrier" ::: "memory")

// h LDS layout (proven R6): 8 chunks of 16 f16 at 48-B stride, conflict-free b128.
#define HCHB  48
#define HBUFI (8 * HCHB / 4)   // 96 ints per buffer

// ---------- prep: transpose W_ih -> wt (V-1 x H) ----------
__global__ __launch_bounds__(256) void prep_kernel(
    const float* __restrict__ W_ih, float* __restrict__ wt)
{
    int idx = blockIdx.x * 256 + threadIdx.x;
    if (idx < WTN) {
        int h = idx / (Vocab - 1);
        int f = idx - h * (Vocab - 1);
        wt[f * Hdim + h] = W_ih[idx];
    }
}

// ---------- decode: one-hot -> pre rows (f16) + syms table. ZERO atomics.
// (R9 lesson: per-pad-row global atomicMin onto 4 cachelines serialized the
// kernel at ~534 us. Length is now computed per-block in the RNN prologue.)
__global__ __launch_bounds__(256) void decode_kernel(
    const float* __restrict__ x, const float* __restrict__ wt,
    uint2* __restrict__ pre_all, int* __restrict__ syms_g)
{
    const int l    = threadIdx.x & 63;
    const int half = l >> 5;
    const int li   = l & 31;
    const int row  = blockIdx.x * 8 + (threadIdx.x >> 6) * 2 + half;  // b*T + t

    const float4* xr = (const float4*)(x + (size_t)row * Vocab);
    float4 v = xr[li];
    int c = v.x > 0.5f ? 0 : v.y > 0.5f ? 1 : v.z > 0.5f ? 2 : v.w > 0.5f ? 3 : -1;
    unsigned long long m = __ballot(c >= 0);
    unsigned mh = half ? (unsigned)(m >> 32) : (unsigned)m;   // each half-wave = one row
    int fl  = __builtin_ctz(mh) + (half << 5);
    int sym = __shfl(li * 4 + c, fl, 64);

    if (li == 0) syms_g[row] = sym;
    if (sym != 0) {
        const float4* wr = (const float4*)(wt + (sym - 1) * Hdim);
        float4 wv = wr[li];    // pre elements 4li..4li+3 (f16 RTE, proven R9)
        unsigned e0 = __builtin_bit_cast(unsigned short, (_Float16)wv.x);
        unsigned e1 = __builtin_bit_cast(unsigned short, (_Float16)wv.y);
        unsigned e2 = __builtin_bit_cast(unsigned short, (_Float16)wv.z);
        unsigned e3 = __builtin_bit_cast(unsigned short, (_Float16)wv.w);
        uint2 o;
        o.x = e0 | (e1 << 16);
        o.y = e2 | (e3 << 16);
        pre_all[(size_t)row * 32 + li] = o;
    }
}

// ---------- RNN: R9's proven loop; length computed in-block from syms ----------
__global__ __launch_bounds__(512, 2) void rnn_kernel(
    const unsigned* __restrict__ pre_all, const int* __restrict__ syms_g,
    const float* __restrict__ W_hh,
    const float* __restrict__ b_ih, const float* __restrict__ b_hh,
    const float* __restrict__ W_out, const float* __restrict__ b_out,
    float* __restrict__ out)
{
    __shared__ __align__(16) int hbuf[2][HBUFI];   // f16 h, double-buffered
    __shared__ int len_sh;

    const int tid = threadIdx.x;
    const int b   = blockIdx.x;
    const int g   = tid >> 3;   // group 0..63, owns outputs 2g, 2g+1
    const int j   = tid & 7;    // K-chunk index (16 elements each)

    if (tid == 0) len_sh = Tlen;
    for (int k = tid; k < 2 * HBUFI; k += 512) ((int*)hbuf)[k] = 0;  // h0 = 0

    // W_hh rows 2g,2g+1, cols [16j,16j+16) -> 16 packed f16x2 (proven pack)
    int wp[16];
    #pragma unroll
    for (int r = 0; r < 2; r++) {
        const float4* wrow = (const float4*)(W_hh + (2 * g + r) * Hdim + 16 * j);
        #pragma unroll
        for (int q4 = 0; q4 < 4; q4++) {
            float4 t4 = wrow[q4];
            wp[r * 8 + q4 * 2 + 0] = __builtin_bit_cast(int, __builtin_amdgcn_cvt_pkrtz(t4.x, t4.y));
            wp[r * 8 + q4 * 2 + 1] = __builtin_bit_cast(int, __builtin_amdgcn_cvt_pkrtz(t4.z, t4.w));
        }
    }
    const float bias0 = b_ih[2 * g]     + b_hh[2 * g];
    const float bias1 = b_ih[2 * g + 1] + b_hh[2 * g + 1];

    __syncthreads();   // len_sh init + hbuf zeros visible

    // length = first t with sym==0 (R6-proven in-block scan, per-CU atomics)
    {
        const int* sb = syms_g + b * Tlen;
        int lm = Tlen;
        #pragma unroll
        for (int k = 0; k < 2; k++) {
            int idx = tid + k * 512;
            if (sb[idx] == 0 && idx < lm) lm = idx;
        }
        if (lm < Tlen) atomicMin(&len_sh, lm);
    }
    __syncthreads();
    const int len = len_sh;

    // pre dword g of row t = f16 elements (2g, 2g+1); depth-4 register ring
    const unsigned* prow = pre_all + (size_t)b * Tlen * 64 + g;
    unsigned q0 = 0, q1 = 0, q2 = 0, q3 = 0;
    if (0 < len) q0 = prow[0];
    if (1 < len) q1 = prow[64];
    if (2 < len) q2 = prow[128];
    if (3 < len) q3 = prow[192];

    const char* hb0 = (const char*)hbuf[0];
    const char* hb1 = (const char*)hbuf[1];
    const int roff = j * HCHB;
    const int woff = (g >> 3) * HCHB + ((2 * g) & 15) * 2;

    for (int t = 0; t < len; t++) {
        #pragma unroll
        for (int k = 0; k < 16; k += 8)
            asm volatile("" : "+v"(wp[k]), "+v"(wp[k+1]), "+v"(wp[k+2]), "+v"(wp[k+3]),
                             "+v"(wp[k+4]), "+v"(wp[k+5]), "+v"(wp[k+6]), "+v"(wp[k+7]));

        unsigned qn = 0;
        if (t + 4 < len) qn = prow[(size_t)(t + 4) * 64];   // in flight 4 steps

        const char* hb = (t & 1) ? hb1 : hb0;
        uint4 r0 = *(const uint4*)(hb + roff);
        uint4 r1 = *(const uint4*)(hb + roff + 16);
        unsigned hr[8] = {r0.x, r0.y, r0.z, r0.w, r1.x, r1.y, r1.z, r1.w};
        float a0 = 0.0f, a1 = 0.0f;
        #pragma unroll
        for (int p = 0; p < 8; p++) {
            half2_t hh = __builtin_bit_cast(half2_t, hr[p]);
            a0 = __builtin_amdgcn_fdot2(hh, __builtin_bit_cast(half2_t, wp[p]),     a0, false);
            a1 = __builtin_amdgcn_fdot2(hh, __builtin_bit_cast(half2_t, wp[8 + p]), a1, false);
        }
        a0 += DPPF(a0, 0xB1);  a1 += DPPF(a1, 0xB1);
        a0 += DPPF(a0, 0x4E);  a1 += DPPF(a1, 0x4E);
        a0 += DPPF(a0, 0x141); a1 += DPPF(a1, 0x141);
        if (j == 0) {
            half2_t ph = __builtin_bit_cast(half2_t, q0);
            float h0 = tanh_fast(a0 + (float)ph.x + bias0);
            float h1 = tanh_fast(a1 + (float)ph.y + bias1);
            int pk = __builtin_bit_cast(int, __builtin_amdgcn_cvt_pkrtz(h0, h1));
            *(int*)(((char*)hbuf[(t + 1) & 1]) + woff) = pk;
        }
        q0 = q1; q1 = q2; q2 = q3; q3 = qn;
        BAR();
    }

    // epilogue (proven R6/R9)
    const _Float16* hf = (const _Float16*)hbuf[len & 1];
    #define HGET(e) ((float)hf[((e) >> 4) * 24 + ((e) & 15)])
    if (tid < Hdim)
        out[2 * Bsz + b * Hdim + tid] = HGET(tid);
    if (tid < 64) {
        float h0 = HGET(tid);
        float h1 = HGET(tid + 64);
        float p0 = W_out[tid] * h0 + W_out[64 + tid] * h1;
        float p1 = W_out[128 + tid] * h0 + W_out[192 + tid] * h1;
        #pragma unroll
        for (int off = 32; off > 0; off >>= 1) {
            p0 += __shfl_down(p0, off, 64);
            p1 += __shfl_down(p1, off, 64);
        }
        if (tid == 0) {
            float l0 = p0 + b_out[0], l1 = p1 + b_out[1];
            float m  = fmaxf(l0, l1);
            float e0 = __expf(l0 - m), e1 = __expf(l1 - m);
            float d  = e0 + e1;
            out[b * 2 + 0] = e0 / d;
            out[b * 2 + 1] = e1 / d;
        }
    }
    #undef HGET
}

// ---------- fallback (R6 exact, proven) ----------
__global__ __launch_bounds__(512, 2) void rnn_fallback(
    const float* __restrict__ x, const float* __restrict__ wt,
    const float* __restrict__ W_hh,
    const float* __restrict__ b_ih, const float* __restrict__ b_hh,
    const float* __restrict__ W_out, const float* __restrict__ b_out,
    float* __restrict__ out)
{
    __shared__ float wt_s[WTN];
    __shared__ int   syms[Tlen];
    __shared__ __align__(16) int hbuf[2][HBUFI];
    __shared__ int   len_sh;

    const int tid = threadIdx.x;
    const int b   = blockIdx.x;
    const int g   = tid >> 3;
    const int j   = tid & 7;

    if (tid == 0) len_sh = Tlen;
    for (int k = tid; k < 2 * HBUFI; k += 512) ((int*)hbuf)[k] = 0;

    int wp[16];
    #pragma unroll
    for (int r = 0; r < 2; r++) {
        const float4* wrow = (const float4*)(W_hh + (2 * g + r) * Hdim + 16 * j);
        #pragma unroll
        for (int q4 = 0; q4 < 4; q4++) {
            float4 t4 = wrow[q4];
            wp[r * 8 + q4 * 2 + 0] = __builtin_bit_cast(int, __builtin_amdgcn_cvt_pkrtz(t4.x, t4.y));
            wp[r * 8 + q4 * 2 + 1] = __builtin_bit_cast(int, __builtin_amdgcn_cvt_pkrtz(t4.z, t4.w));
        }
    }
    const float bias0 = b_ih[2 * g]     + b_hh[2 * g];
    const float bias1 = b_ih[2 * g + 1] + b_hh[2 * g + 1];

    {
        const float4* src = (const float4*)wt;
        float4* dst = (float4*)wt_s;
        for (int k = tid; k < WTN / 4; k += 512) dst[k] = src[k];
    }
    const float4* xb = (const float4*)(x + (size_t)b * Tlen * Vocab);
    for (int k = tid; k < (Tlen * Vocab) / 4; k += 512) {
        float4 v = xb[k];
        int c = -1;
        if      (v.x > 0.5f) c = 0;
        else if (v.y > 0.5f) c = 1;
        else if (v.z > 0.5f) c = 2;
        else if (v.w > 0.5f) c = 3;
        if (c >= 0) syms[k >> 5] = ((k & 31) << 2) + c;
    }
    __syncthreads();
    {
        int lm = Tlen;
        for (int k = tid; k < Tlen; k += 512)
            if (syms[k] == 0 && k < lm) lm = k;
        if (lm < Tlen) atomicMin(&len_sh, lm);
    }
    __syncthreads();
    const int len = len_sh;

    const float2* wt2 = (const float2*)wt_s;
    float2 pre_v = {0.0f, 0.0f}, p_t1 = {0.0f, 0.0f};
    int s_t2 = 1;
    if (len > 0) pre_v = wt2[(syms[0] - 1) * 64 + g];
    if (len > 1) p_t1  = wt2[(syms[1] - 1) * 64 + g];
    if (len > 2) s_t2  = syms[2];

    const char* hb0 = (const char*)hbuf[0];
    const char* hb1 = (const char*)hbuf[1];
    const int roff = j * HCHB;
    const int woff = (g >> 3) * HCHB + ((2 * g) & 15) * 2;

    for (int t = 0; t < len; t++) {
        #pragma unroll
        for (int k = 0; k < 16; k += 8)
            asm volatile("" : "+v"(wp[k]), "+v"(wp[k+1]), "+v"(wp[k+2]), "+v"(wp[k+3]),
                             "+v"(wp[k+4]), "+v"(wp[k+5]), "+v"(wp[k+6]), "+v"(wp[k+7]));
        float2 p_t2 = wt2[(s_t2 - 1) * 64 + g];
        int   s_t3 = (t + 3 < len) ? syms[t + 3] : 1;

        const char* hb = (t & 1) ? hb1 : hb0;
        uint4 r0 = *(const uint4*)(hb + roff);
        uint4 r1 = *(const uint4*)(hb + roff + 16);
        unsigned hr[8] = {r0.x, r0.y, r0.z, r0.w, r1.x, r1.y, r1.z, r1.w};
        float a0 = 0.0f, a1 = 0.0f;
        #pragma unroll
        for (int p = 0; p < 8; p++) {
            half2_t hh = __builtin_bit_cast(half2_t, hr[p]);
            a0 = __builtin_amdgcn_fdot2(hh, __builtin_bit_cast(half2_t, wp[p]),     a0, false);
            a1 = __builtin_amdgcn_fdot2(hh, __builtin_bit_cast(half2_t, wp[8 + p]), a1, false);
        }
        a0 += DPPF(a0, 0xB1); a1 += DPPF(a1, 0xB1);
        a0 += DPPF(a0, 0x4E); a1 += DPPF(a1, 0x4E);
        a0 += DPPF(a0, 0x141); a1 += DPPF(a1, 0x141);
        if (j == 0) {
            float h0 = tanh_fast(a0 + pre_v.x + bias0);
            float h1 = tanh_fast(a1 + pre_v.y + bias1);
            int pk = __builtin_bit_cast(int, __builtin_amdgcn_cvt_pkrtz(h0, h1));
            *(int*)(((char*)hbuf[(t + 1) & 1]) + woff) = pk;
        }
        pre_v = p_t1; p_t1 = p_t2; s_t2 = s_t3;
        __syncthreads();
    }

    const _Float16* hf = (const _Float16*)hbuf[len & 1];
    #define HGET(e) ((float)hf[((e) >> 4) * 24 + ((e) & 15)])
    if (tid < Hdim)
        out[2 * Bsz + b * Hdim + tid] = HGET(tid);
    if (tid < 64) {
        float h0 = HGET(tid);
        float h1 = HGET(tid + 64);
        float p0 = W_out[tid] * h0 + W_out[64 + tid] * h1;
        float p1 = W_out[128 + tid] * h0 + W_out[192 + tid] * h1;
        #pragma unroll
        for (int off = 32; off > 0; off >>= 1) {
            p0 += __shfl_down(p0, off, 64);
            p1 += __shfl_down(p1, off, 64);
        }
        if (tid == 0) {
            float l0 = p0 + b_out[0], l1 = p1 + b_out[1];
            float m  = fmaxf(l0, l1);
            float e0 = __expf(l0 - m), e1 = __expf(l1 - m);
            float d  = e0 + e1;
            out[b * 2 + 0] = e0 / d;
            out[b * 2 + 1] = e1 / d;
        }
    }
    #undef HGET
}

extern "C" void kernel_launch(void* const* d_in, const int* in_sizes, int n_in,
                              void* d_out, int out_size, void* d_ws, size_t ws_size,
                              hipStream_t stream) {
    const float* x     = (const float*)d_in[0];
    const float* W_ih  = (const float*)d_in[1];
    const float* W_hh  = (const float*)d_in[2];
    const float* b_ih  = (const float*)d_in[3];
    const float* b_hh  = (const float*)d_in[4];
    const float* W_out = (const float*)d_in[5];
    const float* b_out = (const float*)d_in[6];
    float* out = (float*)d_out;

    const int NTRN = (WTN + 255) / 256;

    if (ws_size >= WS_NEED) {
        uint2* pre_all = (uint2*)d_ws;
        int*   syms_g  = (int*)((char*)d_ws + SYMS_OFF);
        float* wt      = (float*)((char*)d_ws + WT_OFF);
        prep_kernel<<<NTRN, 256, 0, stream>>>(W_ih, wt);
        decode_kernel<<<(Bsz * Tlen) / 8, 256, 0, stream>>>(x, wt, pre_all, syms_g);
        rnn_kernel<<<Bsz, 512, 0, stream>>>((const unsigned*)pre_all, syms_g,
                                            W_hh, b_ih, b_hh, W_out, b_out, out);
    } else {
        float* wt = (float*)d_ws;
        prep_kernel<<<NTRN, 256, 0, stream>>>(W_ih, wt);
        rnn_fallback<<<Bsz, 512, 0, stream>>>(x, wt, W_hh, b_ih, b_hh,
                                              W_out, b_out, out);
    }
}

// Round 11
// 542.488 us; speedup vs baseline: 1.6806x; 1.1412x over previous
//
#include <hip/hip_runtime.h>
#include <stdint.h>

#define Bsz   256
#define Tlen  1024
#define Vocab 128
#define Hdim  128
#define WTN   ((Vocab - 1) * Hdim)   // 127*128

typedef _Float16 half2_t __attribute__((ext_vector_type(2)));

// ws layout: pre table (64 MiB f16) + syms (1 MiB) + len (1 KiB) + wt (65 KiB)
#define PRE_BYTES ((size_t)Bsz * Tlen * Hdim * 2)
#define SYMS_OFF  PRE_BYTES
#define LEN_OFF   (PRE_BYTES + (size_t)Bsz * Tlen * 4)
#define WT_OFF    (LEN_OFF + 1024)
#define WS_NEED   (WT_OFF + (size_t)WTN * 4 + 256)

__device__ __forceinline__ float tanh_fast(float x) {
    float e = __builtin_amdgcn_exp2f(x * 2.885390081777927f);
    return 1.0f - 2.0f * __builtin_amdgcn_rcpf(e + 1.0f);
}

// DPP quad helpers (proven R6): 0xB1=xor1, 0x4E=xor2, 0x141=row_half_mirror
#define DPPF(x, ctrl) __int_as_float(__builtin_amdgcn_mov_dpp(__float_as_int(x), ctrl, 0xF, 0xF, true))

// lgkm-only barrier (proven R9): does NOT drain vmcnt, so the global pre
// prefetch ring stays in flight across steps.
#define BAR() asm volatile("s_waitcnt lgkmcnt(0)\n\ts_barrier" ::: "memory")

// h LDS layout (proven R6): 8 chunks of 16 f16 at 48-B stride, conflict-free b128.
#define HCHB  48
#define HBUFI (8 * HCHB / 4)   // 96 ints per buffer

// ---------- prep: transpose W_ih -> wt (V-1 x H) ----------
__global__ __launch_bounds__(256) void prep_kernel(
    const float* __restrict__ W_ih, float* __restrict__ wt)
{
    int idx = blockIdx.x * 256 + threadIdx.x;
    if (idx < WTN) {
        int h = idx / (Vocab - 1);
        int f = idx - h * (Vocab - 1);
        wt[f * Hdim + h] = W_ih[idx];
    }
}

// ---------- decode (proven R10): one-hot -> pre rows (f16) + syms. ZERO atomics ----------
__global__ __launch_bounds__(256) void decode_kernel(
    const float* __restrict__ x, const float* __restrict__ wt,
    uint2* __restrict__ pre_all, int* __restrict__ syms_g)
{
    const int l    = threadIdx.x & 63;
    const int half = l >> 5;
    const int li   = l & 31;
    const int row  = blockIdx.x * 8 + (threadIdx.x >> 6) * 2 + half;  // b*T + t

    const float4* xr = (const float4*)(x + (size_t)row * Vocab);
    float4 v = xr[li];
    int c = v.x > 0.5f ? 0 : v.y > 0.5f ? 1 : v.z > 0.5f ? 2 : v.w > 0.5f ? 3 : -1;
    unsigned long long m = __ballot(c >= 0);
    unsigned mh = half ? (unsigned)(m >> 32) : (unsigned)m;   // each half-wave = one row
    int fl  = __builtin_ctz(mh) + (half << 5);
    int sym = __shfl(li * 4 + c, fl, 64);

    if (li == 0) syms_g[row] = sym;
    if (sym != 0) {
        const float4* wr = (const float4*)(wt + (sym - 1) * Hdim);
        float4 wv = wr[li];    // pre elements 4li..4li+3 (f16 RTE, proven R9)
        unsigned e0 = __builtin_bit_cast(unsigned short, (_Float16)wv.x);
        unsigned e1 = __builtin_bit_cast(unsigned short, (_Float16)wv.y);
        unsigned e2 = __builtin_bit_cast(unsigned short, (_Float16)wv.z);
        unsigned e3 = __builtin_bit_cast(unsigned short, (_Float16)wv.w);
        uint2 o;
        o.x = e0 | (e1 << 16);
        o.y = e2 | (e3 << 16);
        pre_all[(size_t)row * 32 + li] = o;
    }
}

// ---------- length kernel: one block per sequence, in-LDS min (per-CU atomics) ----------
__global__ __launch_bounds__(256) void len_kernel(
    const int* __restrict__ syms_g, int* __restrict__ len_g)
{
    __shared__ int len_sh;
    const int b = blockIdx.x;
    if (threadIdx.x == 0) len_sh = Tlen;
    __syncthreads();
    const int* sb = syms_g + b * Tlen;
    int lm = Tlen;
    #pragma unroll
    for (int k = 0; k < 4; k++) {
        int idx = threadIdx.x + k * 256;
        if (sb[idx] == 0 && idx < lm) lm = idx;
    }
    if (lm < Tlen) atomicMin(&len_sh, lm);
    __syncthreads();
    if (threadIdx.x == 0) len_g[b] = len_sh;
}

// ---------- RNN: R9's kernel VERBATIM (proven 236 us allocation) ----------
__global__ __launch_bounds__(512, 2) void rnn_kernel(
    const unsigned* __restrict__ pre_all, const int* __restrict__ len_g,
    const float* __restrict__ W_hh,
    const float* __restrict__ b_ih, const float* __restrict__ b_hh,
    const float* __restrict__ W_out, const float* __restrict__ b_out,
    float* __restrict__ out)
{
    __shared__ __align__(16) int hbuf[2][HBUFI];   // f16 h, double-buffered

    const int tid = threadIdx.x;
    const int b   = blockIdx.x;
    const int g   = tid >> 3;   // group 0..63, owns outputs 2g, 2g+1
    const int j   = tid & 7;    // K-chunk index (16 elements each)

    for (int k = tid; k < 2 * HBUFI; k += 512) ((int*)hbuf)[k] = 0;  // h0 = 0

    // W_hh rows 2g,2g+1, cols [16j,16j+16) -> 16 packed f16x2 (proven pack)
    int wp[16];
    #pragma unroll
    for (int r = 0; r < 2; r++) {
        const float4* wrow = (const float4*)(W_hh + (2 * g + r) * Hdim + 16 * j);
        #pragma unroll
        for (int q4 = 0; q4 < 4; q4++) {
            float4 t4 = wrow[q4];
            wp[r * 8 + q4 * 2 + 0] = __builtin_bit_cast(int, __builtin_amdgcn_cvt_pkrtz(t4.x, t4.y));
            wp[r * 8 + q4 * 2 + 1] = __builtin_bit_cast(int, __builtin_amdgcn_cvt_pkrtz(t4.z, t4.w));
        }
    }
    const float bias0 = b_ih[2 * g]     + b_hh[2 * g];
    const float bias1 = b_ih[2 * g + 1] + b_hh[2 * g + 1];

    const int len = len_g[b];
    // pre dword g of row t = f16 elements (2g, 2g+1) — same mapping as R6's wt2
    const unsigned* prow = pre_all + (size_t)b * Tlen * 64 + g;

    unsigned q0 = 0, q1 = 0, q2 = 0, q3 = 0;
    if (0 < len) q0 = prow[0];
    if (1 < len) q1 = prow[64];
    if (2 < len) q2 = prow[128];
    if (3 < len) q3 = prow[192];

    const char* hb0 = (const char*)hbuf[0];
    const char* hb1 = (const char*)hbuf[1];
    const int roff = j * HCHB;
    const int woff = (g >> 3) * HCHB + ((2 * g) & 15) * 2;

    __syncthreads();   // once: h0 + W visible

    for (int t = 0; t < len; t++) {
        #pragma unroll
        for (int k = 0; k < 16; k += 8)
            asm volatile("" : "+v"(wp[k]), "+v"(wp[k+1]), "+v"(wp[k+2]), "+v"(wp[k+3]),
                             "+v"(wp[k+4]), "+v"(wp[k+5]), "+v"(wp[k+6]), "+v"(wp[k+7]));

        unsigned qn = 0;
        if (t + 4 < len) qn = prow[(size_t)(t + 4) * 64];   // stays in flight 4 steps

        const char* hb = (t & 1) ? hb1 : hb0;
        uint4 r0 = *(const uint4*)(hb + roff);
        uint4 r1 = *(const uint4*)(hb + roff + 16);
        unsigned hr[8] = {r0.x, r0.y, r0.z, r0.w, r1.x, r1.y, r1.z, r1.w};
        float a0 = 0.0f, a1 = 0.0f;
        #pragma unroll
        for (int p = 0; p < 8; p++) {
            half2_t hh = __builtin_bit_cast(half2_t, hr[p]);
            a0 = __builtin_amdgcn_fdot2(hh, __builtin_bit_cast(half2_t, wp[p]),     a0, false);
            a1 = __builtin_amdgcn_fdot2(hh, __builtin_bit_cast(half2_t, wp[8 + p]), a1, false);
        }
        a0 += DPPF(a0, 0xB1);  a1 += DPPF(a1, 0xB1);
        a0 += DPPF(a0, 0x4E);  a1 += DPPF(a1, 0x4E);
        a0 += DPPF(a0, 0x141); a1 += DPPF(a1, 0x141);
        if (j == 0) {
            half2_t ph = __builtin_bit_cast(half2_t, q0);
            float h0 = tanh_fast(a0 + (float)ph.x + bias0);
            float h1 = tanh_fast(a1 + (float)ph.y + bias1);
            int pk = __builtin_bit_cast(int, __builtin_amdgcn_cvt_pkrtz(h0, h1));
            *(int*)(((char*)hbuf[(t + 1) & 1]) + woff) = pk;
        }
        q0 = q1; q1 = q2; q2 = q3; q3 = qn;
        BAR();
    }

    // epilogue (proven R6/R9)
    const _Float16* hf = (const _Float16*)hbuf[len & 1];
    #define HGET(e) ((float)hf[((e) >> 4) * 24 + ((e) & 15)])
    if (tid < Hdim)
        out[2 * Bsz + b * Hdim + tid] = HGET(tid);
    if (tid < 64) {
        float h0 = HGET(tid);
        float h1 = HGET(tid + 64);
        float p0 = W_out[tid] * h0 + W_out[64 + tid] * h1;
        float p1 = W_out[128 + tid] * h0 + W_out[192 + tid] * h1;
        #pragma unroll
        for (int off = 32; off > 0; off >>= 1) {
            p0 += __shfl_down(p0, off, 64);
            p1 += __shfl_down(p1, off, 64);
        }
        if (tid == 0) {
            float l0 = p0 + b_out[0], l1 = p1 + b_out[1];
            float m  = fmaxf(l0, l1);
            float e0 = __expf(l0 - m), e1 = __expf(l1 - m);
            float d  = e0 + e1;
            out[b * 2 + 0] = e0 / d;
            out[b * 2 + 1] = e1 / d;
        }
    }
    #undef HGET
}

// ---------- fallback (R6 exact, proven) ----------
__global__ __launch_bounds__(512, 2) void rnn_fallback(
    const float* __restrict__ x, const float* __restrict__ wt,
    const float* __restrict__ W_hh,
    const float* __restrict__ b_ih, const float* __restrict__ b_hh,
    const float* __restrict__ W_out, const float* __restrict__ b_out,
    float* __restrict__ out)
{
    __shared__ float wt_s[WTN];
    __shared__ int   syms[Tlen];
    __shared__ __align__(16) int hbuf[2][HBUFI];
    __shared__ int   len_sh;

    const int tid = threadIdx.x;
    const int b   = blockIdx.x;
    const int g   = tid >> 3;
    const int j   = tid & 7;

    if (tid == 0) len_sh = Tlen;
    for (int k = tid; k < 2 * HBUFI; k += 512) ((int*)hbuf)[k] = 0;

    int wp[16];
    #pragma unroll
    for (int r = 0; r < 2; r++) {
        const float4* wrow = (const float4*)(W_hh + (2 * g + r) * Hdim + 16 * j);
        #pragma unroll
        for (int q4 = 0; q4 < 4; q4++) {
            float4 t4 = wrow[q4];
            wp[r * 8 + q4 * 2 + 0] = __builtin_bit_cast(int, __builtin_amdgcn_cvt_pkrtz(t4.x, t4.y));
            wp[r * 8 + q4 * 2 + 1] = __builtin_bit_cast(int, __builtin_amdgcn_cvt_pkrtz(t4.z, t4.w));
        }
    }
    const float bias0 = b_ih[2 * g]     + b_hh[2 * g];
    const float bias1 = b_ih[2 * g + 1] + b_hh[2 * g + 1];

    {
        const float4* src = (const float4*)wt;
        float4* dst = (float4*)wt_s;
        for (int k = tid; k < WTN / 4; k += 512) dst[k] = src[k];
    }
    const float4* xb = (const float4*)(x + (size_t)b * Tlen * Vocab);
    for (int k = tid; k < (Tlen * Vocab) / 4; k += 512) {
        float4 v = xb[k];
        int c = -1;
        if      (v.x > 0.5f) c = 0;
        else if (v.y > 0.5f) c = 1;
        else if (v.z > 0.5f) c = 2;
        else if (v.w > 0.5f) c = 3;
        if (c >= 0) syms[k >> 5] = ((k & 31) << 2) + c;
    }
    __syncthreads();
    {
        int lm = Tlen;
        for (int k = tid; k < Tlen; k += 512)
            if (syms[k] == 0 && k < lm) lm = k;
        if (lm < Tlen) atomicMin(&len_sh, lm);
    }
    __syncthreads();
    const int len = len_sh;

    const float2* wt2 = (const float2*)wt_s;
    float2 pre_v = {0.0f, 0.0f}, p_t1 = {0.0f, 0.0f};
    int s_t2 = 1;
    if (len > 0) pre_v = wt2[(syms[0] - 1) * 64 + g];
    if (len > 1) p_t1  = wt2[(syms[1] - 1) * 64 + g];
    if (len > 2) s_t2  = syms[2];

    const char* hb0 = (const char*)hbuf[0];
    const char* hb1 = (const char*)hbuf[1];
    const int roff = j * HCHB;
    const int woff = (g >> 3) * HCHB + ((2 * g) & 15) * 2;

    for (int t = 0; t < len; t++) {
        #pragma unroll
        for (int k = 0; k < 16; k += 8)
            asm volatile("" : "+v"(wp[k]), "+v"(wp[k+1]), "+v"(wp[k+2]), "+v"(wp[k+3]),
                             "+v"(wp[k+4]), "+v"(wp[k+5]), "+v"(wp[k+6]), "+v"(wp[k+7]));
        float2 p_t2 = wt2[(s_t2 - 1) * 64 + g];
        int   s_t3 = (t + 3 < len) ? syms[t + 3] : 1;

        const char* hb = (t & 1) ? hb1 : hb0;
        uint4 r0 = *(const uint4*)(hb + roff);
        uint4 r1 = *(const uint4*)(hb + roff + 16);
        unsigned hr[8] = {r0.x, r0.y, r0.z, r0.w, r1.x, r1.y, r1.z, r1.w};
        float a0 = 0.0f, a1 = 0.0f;
        #pragma unroll
        for (int p = 0; p < 8; p++) {
            half2_t hh = __builtin_bit_cast(half2_t, hr[p]);
            a0 = __builtin_amdgcn_fdot2(hh, __builtin_bit_cast(half2_t, wp[p]),     a0, false);
            a1 = __builtin_amdgcn_fdot2(hh, __builtin_bit_cast(half2_t, wp[8 + p]), a1, false);
        }
        a0 += DPPF(a0, 0xB1); a1 += DPPF(a1, 0xB1);
        a0 += DPPF(a0, 0x4E); a1 += DPPF(a1, 0x4E);
        a0 += DPPF(a0, 0x141); a1 += DPPF(a1, 0x141);
        if (j == 0) {
            float h0 = tanh_fast(a0 + pre_v.x + bias0);
            float h1 = tanh_fast(a1 + pre_v.y + bias1);
            int pk = __builtin_bit_cast(int, __builtin_amdgcn_cvt_pkrtz(h0, h1));
            *(int*)(((char*)hbuf[(t + 1) & 1]) + woff) = pk;
        }
        pre_v = p_t1; p_t1 = p_t2; s_t2 = s_t3;
        __syncthreads();
    }

    const _Float16* hf = (const _Float16*)hbuf[len & 1];
    #define HGET(e) ((float)hf[((e) >> 4) * 24 + ((e) & 15)])
    if (tid < Hdim)
        out[2 * Bsz + b * Hdim + tid] = HGET(tid);
    if (tid < 64) {
        float h0 = HGET(tid);
        float h1 = HGET(tid + 64);
        float p0 = W_out[tid] * h0 + W_out[64 + tid] * h1;
        float p1 = W_out[128 + tid] * h0 + W_out[192 + tid] * h1;
        #pragma unroll
        for (int off = 32; off > 0; off >>= 1) {
            p0 += __shfl_down(p0, off, 64);
            p1 += __shfl_down(p1, off, 64);
        }
        if (tid == 0) {
            float l0 = p0 + b_out[0], l1 = p1 + b_out[1];
            float m  = fmaxf(l0, l1);
            float e0 = __expf(l0 - m), e1 = __expf(l1 - m);
            float d  = e0 + e1;
            out[b * 2 + 0] = e0 / d;
            out[b * 2 + 1] = e1 / d;
        }
    }
    #undef HGET
}

extern "C" void kernel_launch(void* const* d_in, const int* in_sizes, int n_in,
                              void* d_out, int out_size, void* d_ws, size_t ws_size,
                              hipStream_t stream) {
    const float* x     = (const float*)d_in[0];
    const float* W_ih  = (const float*)d_in[1];
    const float* W_hh  = (const float*)d_in[2];
    const float* b_ih  = (const float*)d_in[3];
    const float* b_hh  = (const float*)d_in[4];
    const float* W_out = (const float*)d_in[5];
    const float* b_out = (const float*)d_in[6];
    float* out = (float*)d_out;

    const int NTRN = (WTN + 255) / 256;

    if (ws_size >= WS_NEED) {
        uint2* pre_all = (uint2*)d_ws;
        int*   syms_g  = (int*)((char*)d_ws + SYMS_OFF);
        int*   len_g   = (int*)((char*)d_ws + LEN_OFF);
        float* wt      = (float*)((char*)d_ws + WT_OFF);
        prep_kernel<<<NTRN, 256, 0, stream>>>(W_ih, wt);
        decode_kernel<<<(Bsz * Tlen) / 8, 256, 0, stream>>>(x, wt, pre_all, syms_g);
        len_kernel<<<Bsz, 256, 0, stream>>>(syms_g, len_g);
        rnn_kernel<<<Bsz, 512, 0, stream>>>((const unsigned*)pre_all, len_g,
                                            W_hh, b_ih, b_hh, W_out, b_out, out);
    } else {
        float* wt = (float*)d_ws;
        prep_kernel<<<NTRN, 256, 0, stream>>>(W_ih, wt);
        rnn_fallback<<<Bsz, 512, 0, stream>>>(x, wt, W_hh, b_ih, b_hh,
                                              W_out, b_out, out);
    }
}